// Round 5
// baseline (392.560 us; speedup 1.0000x reference)
//
#include <hip/hip_runtime.h>
#include <math.h>

#define NUM_EMB 1024
#define EMB_DIM 256
#define NROWS   65536
#define NTHREADS 256
#define EPSF 1.5e-3f
#define GCAP 524288
#define LLCAP 512

// out layout (float32, concatenated):
#define OFF_IDX  16777216
#define OFF_VQ   16842752

// ws layout (bytes):
#define WS_C2    0         // float[1024]  ||e_k||^2 sequential fp32 (verified R3)
#define WS_HIST  4096      // int[1024]
#define WS_LOSS  8192      // float
#define WS_GCNT  8196      // int
#define WS_R2    8448      // float[65536] numpy-pairwise ||z_n||^2 (verified R3)
#define WS_SLOT  270592    // ull[65536]  packed (dist_bits<<32)|k
#define WS_ETF   794880    // float[1024][256]  emb^T fp32
#define WS_ETB   1843456   // ushort[1024][256] emb^T bf16
#define WS_GLIST 2367744   // uint[GCAP] packed (row<<10)|k

typedef __attribute__((ext_vector_type(8))) short bf16x8;
typedef __attribute__((ext_vector_type(4))) float f32x4;

__device__ __forceinline__ unsigned short f2bf(float x) {
  unsigned u = __float_as_uint(x);
  unsigned r = (u + 0x7FFFu + ((u >> 16) & 1u)) >> 16;
  return (unsigned short)r;
}

// transpose emb [256][1024] -> embTf fp32 [1024][256] + embTbf bf16
__global__ __launch_bounds__(NTHREADS) void vq_tr(
    const float* __restrict__ emb, float* __restrict__ embTf,
    unsigned short* __restrict__ embTbf) {
  __shared__ float t[64][65];
  const int kt = blockIdx.x & 15, dt = blockIdx.x >> 4;
  const int tid = threadIdx.x;
  #pragma unroll
  for (int it = 0; it < 16; ++it) {
    int i = tid + it * NTHREADS, r = i >> 6, c = i & 63;
    t[r][c] = emb[(dt * 64 + r) * NUM_EMB + kt * 64 + c];
  }
  __syncthreads();
  #pragma unroll
  for (int it = 0; it < 16; ++it) {
    int i = tid + it * NTHREADS, r = i >> 6, c = i & 63;
    float v = t[c][r];
    embTf[(kt * 64 + r) * EMB_DIM + dt * 64 + c] = v;
    embTbf[(kt * 64 + r) * EMB_DIM + dt * 64 + c] = f2bf(v);
  }
}

// c2[k] = sequential-d fp32 sum of fl(e[d,k]^2); same values+order as R3,
// but read from contiguous embT rows. Also zeros hist/loss/gcnt.
__global__ __launch_bounds__(NTHREADS) void vq_prep2(
    const float* __restrict__ embTf, float* __restrict__ cvec,
    int* __restrict__ hist, float* __restrict__ loss, int* __restrict__ gcnt) {
  int k = blockIdx.x * NTHREADS + threadIdx.x;
  const float4* row = (const float4*)(embTf + (size_t)k * EMB_DIM);
  float s = 0.f;
  #pragma unroll 8
  for (int i = 0; i < 64; ++i) {
    float4 v = row[i];
    s = __fadd_rn(s, __fmul_rn(v.x, v.x));
    s = __fadd_rn(s, __fmul_rn(v.y, v.y));
    s = __fadd_rn(s, __fmul_rn(v.z, v.z));
    s = __fadd_rn(s, __fmul_rn(v.w, v.w));
  }
  cvec[k] = s;
  hist[k] = 0;
  if (k == 0) { *loss = 0.f; *gcnt = 0; }
}

// Barrier-free bf16 MFMA sweep. Block = 64 rows x 1024 codes; wave w owns
// codes [w*256, w*256+256). B fragments loaded directly from global (L2-hot).
// Also computes r2 (numpy pairwise, R3-verified) during the prologue.
__global__ __launch_bounds__(NTHREADS, 3) void vq_mfma(
    const float* __restrict__ z, const unsigned short* __restrict__ embTbf,
    const float* __restrict__ cvec, float* __restrict__ r2out,
    unsigned long long* __restrict__ slots,
    int* __restrict__ gcnt, unsigned int* __restrict__ glist) {
  __shared__ unsigned short zc[64][264];   // A bf16 [m][k], stride 264 (16B-aligned, 2-way-free)
  __shared__ float c2s[NUM_EMB];           // ||e||^2 + 1.0 (positive -> int-bit monotone)
  __shared__ int rowminb[64];              // shared running row-min (float bits)
  __shared__ float pmm[64][2][4];          // r2 pairwise partials
  __shared__ unsigned int llist[4][LLCAP]; // per-wave capture lists
  __shared__ int lcnt[4];

  const int tid = threadIdx.x;
  const int wave = tid >> 6, lane = tid & 63;
  const int quad = lane >> 4, l15 = lane & 15;
  const int n0 = blockIdx.x * 64;
  const float* zblk = z + (size_t)n0 * EMB_DIM;

  // ---- prologue: A-stage fp32->bf16, r2 partials, c2s, inits ----
  #pragma unroll
  for (int it = 0; it < 16; ++it) {
    int g = tid + it * NTHREADS, row = g >> 6, f4 = g & 63;
    float4 v = *(const float4*)(zblk + row * EMB_DIM + f4 * 4);
    ushort4 b; b.x = f2bf(v.x); b.y = f2bf(v.y); b.z = f2bf(v.z); b.w = f2bf(v.w);
    *(ushort4*)(&zc[row][f4 * 4]) = b;
  }
  {
    const int prow = tid >> 2, pm = tid & 3;
    float racc[2][2] = {{0.f, 0.f}, {0.f, 0.f}};
    for (int dc = 0; dc < 8; ++dc) {
      const int half = dc >> 2;
      #pragma unroll
      for (int q = 0; q < 4; ++q)
        #pragma unroll
        for (int jj = 0; jj < 2; ++jj) {
          float v = zblk[prow * EMB_DIM + dc * 32 + q * 8 + pm * 2 + jj];
          racc[half][jj] = __fadd_rn(racc[half][jj], __fmul_rn(v, v));
        }
    }
    pmm[prow][0][pm] = __fadd_rn(racc[0][0], racc[0][1]);
    pmm[prow][1][pm] = __fadd_rn(racc[1][0], racc[1][1]);
  }
  for (int i = tid; i < NUM_EMB; i += NTHREADS) c2s[i] = cvec[i] + 1.0f;
  if (tid < 64) rowminb[tid] = 0x7F000000;
  if (tid < 4) lcnt[tid] = 0;
  __syncthreads();                          // the ONLY block barrier
  if (tid < 64) {
    float h0 = __fadd_rn(__fadd_rn(pmm[tid][0][0], pmm[tid][0][1]),
                         __fadd_rn(pmm[tid][0][2], pmm[tid][0][3]));
    float h1 = __fadd_rn(__fadd_rn(pmm[tid][1][0], pmm[tid][1][1]),
                         __fadd_rn(pmm[tid][1][2], pmm[tid][1][3]));
    r2out[n0 + tid] = __fadd_rn(h0, h1);
    slots[n0 + tid] = ~0ULL;
  }

  // ---- main: per wave, 4 subtiles of 64 codes; no barriers ----
  const int cbase = wave * 256;
  for (int jt = 0; jt < 4; ++jt) {
    const int c0 = cbase + jt * 64;
    f32x4 acc[4][4];
    #pragma unroll
    for (int rt = 0; rt < 4; ++rt)
      #pragma unroll
      for (int ct = 0; ct < 4; ++ct)
        acc[rt][ct] = (f32x4){0.f, 0.f, 0.f, 0.f};

    #pragma unroll
    for (int kc = 0; kc < 8; ++kc) {
      bf16x8 av[4], bv[4];
      #pragma unroll
      for (int ct = 0; ct < 4; ++ct)
        bv[ct] = *(const bf16x8*)(embTbf + (size_t)(c0 + ct * 16 + l15) * EMB_DIM
                                  + kc * 32 + quad * 8);
      #pragma unroll
      for (int rt = 0; rt < 4; ++rt)
        av[rt] = *(const bf16x8*)(&zc[rt * 16 + l15][kc * 32 + quad * 8]);
      #pragma unroll
      for (int rt = 0; rt < 4; ++rt)
        #pragma unroll
        for (int ct = 0; ct < 4; ++ct)
          acc[rt][ct] = __builtin_amdgcn_mfma_f32_16x16x32_bf16(av[rt], bv[ct], acc[rt][ct], 0, 0, 0);
    }

    // epilogue: dist = 1 + c2 - 2s; shared running row-min; capture
    #pragma unroll
    for (int rt = 0; rt < 4; ++rt)
      #pragma unroll
      for (int reg = 0; reg < 4; ++reg) {
        const int rowl = rt * 16 + quad * 4 + reg;
        float d[4];
        #pragma unroll
        for (int ct = 0; ct < 4; ++ct)
          d[ct] = fmaf(-2.f, acc[rt][ct][reg], c2s[c0 + ct * 16 + l15]);
        float m = fminf(fminf(d[0], d[1]), fminf(d[2], d[3]));
        #pragma unroll
        for (int off = 1; off < 16; off <<= 1)
          m = fminf(m, __shfl_xor(m, off));
        if (l15 == 0) atomicMin(&rowminb[rowl], __float_as_int(m));
        float thr = __int_as_float(rowminb[rowl]) + EPSF;  // own atomic visible (in-order lgkm)
        #pragma unroll
        for (int ct = 0; ct < 4; ++ct) {
          if (d[ct] <= thr) {
            int id = atomicAdd(&lcnt[wave], 1);
            if (id < LLCAP)
              llist[wave][id] = ((unsigned)(n0 + rowl) << 10) | (unsigned)(c0 + ct * 16 + l15);
          }
        }
      }
  }

  // per-wave flush (all own-wave LDS ops complete in order)
  int cnt = lcnt[wave]; if (cnt > LLCAP) cnt = LLCAP;
  int base = 0;
  if (lane == 0) base = atomicAdd(gcnt, cnt);
  base = __shfl(base, 0);
  for (int i = lane; i < cnt; i += 64)
    if (base + i < GCAP) glist[base + i] = llist[wave][i];
}

// exact numpy-fp32 re-evaluation of captured pairs [arithmetic verified R3]
__global__ __launch_bounds__(NTHREADS) void vq_refine(
    const float* __restrict__ z, const float* __restrict__ embTf,
    const float* __restrict__ r2, const float* __restrict__ cvec,
    const int* __restrict__ gcnt, const unsigned int* __restrict__ glist,
    unsigned long long* __restrict__ slots) {
  int n = *gcnt; if (n > GCAP) n = GCAP;
  for (int i = blockIdx.x * NTHREADS + threadIdx.x; i < n;
       i += gridDim.x * NTHREADS) {
    unsigned e = glist[i];
    int grow = (int)(e >> 10), k = (int)(e & 1023);
    const float* zr = z + (size_t)grow * EMB_DIM;
    const float* er = embTf + (size_t)k * EMB_DIM;
    float s = 0.f;
    #pragma unroll 8
    for (int d4 = 0; d4 < 64; ++d4) {      // strict sequential-d fmaf chain
      float4 a = *(const float4*)(zr + d4 * 4);
      float4 b = *(const float4*)(er + d4 * 4);
      s = fmaf(a.x, b.x, s); s = fmaf(a.y, b.y, s);
      s = fmaf(a.z, b.z, s); s = fmaf(a.w, b.w, s);
    }
    float dist = __fsub_rn(__fadd_rn(r2[grow], cvec[k]), __fmul_rn(2.0f, s));
    unsigned long long key =
        ((unsigned long long)__float_as_uint(dist) << 32) | (unsigned)k;
    atomicMin(&slots[grow], key);
  }
}

// final index + gather + straight-through write + loss + histogram
__global__ __launch_bounds__(NTHREADS) void vq_epi(
    const float* __restrict__ z, const float* __restrict__ embTf,
    const unsigned long long* __restrict__ slots,
    float* __restrict__ out, int* __restrict__ hist, float* __restrict__ loss) {
  __shared__ int ks[64];
  __shared__ float wsum[4];
  const int tid = threadIdx.x;
  const int n0 = blockIdx.x * 64;
  const float* zrow = z + (size_t)n0 * EMB_DIM;
  if (tid < 64) {
    int k = (int)(slots[n0 + tid] & 1023ULL);
    ks[tid] = k;
    out[OFF_IDX + n0 + tid] = (float)k;
    atomicAdd(&hist[k], 1);
  }
  __syncthreads();
  float sumsq = 0.f;
  #pragma unroll
  for (int it = 0; it < 16; ++it) {
    int g = tid + it * NTHREADS;
    int row = g >> 6;
    int d = (g & 63) * 4;
    int k = ks[row];
    float4 zv = *(const float4*)(zrow + row * EMB_DIM + d);
    float4 q = *(const float4*)(embTf + (size_t)k * EMB_DIM + d);
    float4 df;
    df.x = q.x - zv.x; df.y = q.y - zv.y; df.z = q.z - zv.z; df.w = q.w - zv.w;
    sumsq = fmaf(df.x, df.x, sumsq);
    sumsq = fmaf(df.y, df.y, sumsq);
    sumsq = fmaf(df.z, df.z, sumsq);
    sumsq = fmaf(df.w, df.w, sumsq);
    *(float4*)(out + (size_t)(n0 + row) * EMB_DIM + d) = q;
  }
  #pragma unroll
  for (int off = 32; off > 0; off >>= 1) sumsq += __shfl_down(sumsq, off);
  if ((tid & 63) == 0) wsum[tid >> 6] = sumsq;
  __syncthreads();
  if (tid == 0) atomicAdd(loss, wsum[0] + wsum[1] + wsum[2] + wsum[3]);
}

__global__ __launch_bounds__(NTHREADS) void vq_finalize(
    const int* __restrict__ hist, const float* __restrict__ loss,
    float* __restrict__ out) {
  __shared__ float ws[4];
  int tid = threadIdx.x;
  float s = 0.f;
  for (int k = tid; k < NUM_EMB; k += NTHREADS) {
    float p = (float)hist[k] * (1.0f / 65536.0f);
    s += p * logf(p + 1e-10f);
  }
  #pragma unroll
  for (int off = 32; off > 0; off >>= 1) s += __shfl_down(s, off);
  if ((tid & 63) == 0) ws[tid >> 6] = s;
  __syncthreads();
  if (tid == 0) {
    float tot = ws[0] + ws[1] + ws[2] + ws[3];
    float vq = *loss * (1.0f / 16777216.0f);
    out[OFF_VQ + 0] = vq;
    out[OFF_VQ + 1] = 0.25f * vq;
    out[OFF_VQ + 2] = expf(-tot);
  }
}

extern "C" void kernel_launch(void* const* d_in, const int* in_sizes, int n_in,
                              void* d_out, int out_size, void* d_ws, size_t ws_size,
                              hipStream_t stream) {
  const float* z   = (const float*)d_in[0];
  const float* emb = (const float*)d_in[1];
  float* out = (float*)d_out;
  char* ws = (char*)d_ws;
  float* cvec   = (float*)(ws + WS_C2);
  int*   hist   = (int*)(ws + WS_HIST);
  float* loss   = (float*)(ws + WS_LOSS);
  int*   gcnt   = (int*)(ws + WS_GCNT);
  float* r2     = (float*)(ws + WS_R2);
  unsigned long long* slots = (unsigned long long*)(ws + WS_SLOT);
  float* embTf  = (float*)(ws + WS_ETF);
  unsigned short* embTbf = (unsigned short*)(ws + WS_ETB);
  unsigned int* glist = (unsigned int*)(ws + WS_GLIST);

  vq_tr<<<64, NTHREADS, 0, stream>>>(emb, embTf, embTbf);
  vq_prep2<<<4, NTHREADS, 0, stream>>>(embTf, cvec, hist, loss, gcnt);
  vq_mfma<<<NROWS / 64, NTHREADS, 0, stream>>>(z, embTbf, cvec, r2, slots, gcnt, glist);
  vq_refine<<<1024, NTHREADS, 0, stream>>>(z, embTf, r2, cvec, gcnt, glist, slots);
  vq_epi<<<NROWS / 64, NTHREADS, 0, stream>>>(z, embTf, slots, out, hist, loss);
  vq_finalize<<<1, NTHREADS, 0, stream>>>(hist, loss, out);
}